// Round 2
// baseline (206.689 us; speedup 1.0000x reference)
//
#include <hip/hip_runtime.h>

#define WN 128
#define KN 32
#define CN 9
#define NBND 129           // W+1 boundary positions
#define NEGF (-1e30f)

// jnp floor-mod based wrap: (x + pi) % (2pi) - pi
__device__ __forceinline__ float wrapf(float x) {
    const float PIf  = 3.14159265358979323846f;
    const float TPIf = 6.28318530717958647692f;
    float a = x + PIf;
    float r = fmodf(a, TPIf);
    if (r < 0.0f) r += TPIf;
    return r - PIf;
}

// Kernel 1 (massively parallel): zero the 135MB output, compute edge masks
// E[b][w][kn] as 32-bit kp-masks via ballot, and pack snr[b][w][k].
// grid = B*127 blocks x 1024 threads; block (b,w) owns the 32x32 edge tile.
__global__ __launch_bounds__(1024) void edge_kernel(const float* __restrict__ tok,
                                                    unsigned* __restrict__ Em,
                                                    float* __restrict__ snrP,
                                                    float4* __restrict__ outz,
                                                    int total4) {
    // ---- zero-fill slice of output (write-bound, overlaps edge compute)
    int gid = blockIdx.x * 1024 + threadIdx.x;
    int gsz = gridDim.x * 1024;
    float4 z = make_float4(0.f, 0.f, 0.f, 0.f);
    for (int i = gid; i < total4; i += gsz) outz[i] = z;

    // ---- edge feasibility
    const int b = blockIdx.x / 127;
    const int w = blockIdx.x - b * 127;        // 0..126 (prev window)
    const int t = threadIdx.x;
    const int kp = t & 31;                     // prev token
    const int kn = t >> 5;                     // cur token (0..31)
    const float* Tp = tok + (((size_t)b * WN + w) * KN + kp) * CN;
    const float* Tc = tok + (((size_t)b * WN + w + 1) * KN + kn) * CN;

    float fe = Tp[4], fs = Tc[3];
    float fm = (fe + fs) * 0.5f;
    bool ok_f = (fm <= 0.0f) || (fabsf(fe - fs) / (fm > 0.0f ? fm : 1.0f) <= 0.05f);
    float dphi = wrapf(Tc[7] - Tp[8]);
    bool ok_p = fabsf(dphi) <= 0.5f;
    float ae = Tp[6], an = Tc[5];
    float am = fmaxf(ae, an);
    bool ok_a = (am <= 0.0f) || (fabsf(ae - an) / (am > 0.0f ? am : 1.0f) <= 0.5f);
    bool ok = (Tp[0] > 0.0f) && (Tc[0] > 0.0f) && ok_f && ok_p && ok_a;

    unsigned long long bal = __ballot(ok);     // bit i = lane i (kp) of this wave
    int lw = t & 63;
    if (lw == 0)       Em[((size_t)b * 127 + w) * KN + kn] = (unsigned)(bal & 0xffffffffull);
    else if (lw == 32) Em[((size_t)b * 127 + w) * KN + kn] = (unsigned)(bal >> 32);

    // packed snr: cur window (w+1) by kp==0 lanes; window 0 by block w==0
    if (kp == 0) snrP[((size_t)b * WN + (w + 1)) * KN + kn] = Tc[0];
    if (w == 0 && t < KN) snrP[(size_t)b * WN * KN + t] = tok[(((size_t)b * WN) * KN + t) * CN + 0];
}

// Kernel 2: one wave per batch, barrier-free Viterbi DP + per-root greedy +
// backtrack + phase cumsum + sparse anchor writes.
__global__ __launch_bounds__(64) void dp_kernel(const float* __restrict__ tok,
                                                const unsigned* __restrict__ Em,
                                                const float* __restrict__ snrP,
                                                float* __restrict__ out) {
    const int b = blockIdx.x;
    const int lane = threadIdx.x;

    __shared__ unsigned sm_mask[127 * KN];
    __shared__ float sm_snr[WN * KN];
    __shared__ signed char s_prev[WN][KN];
    __shared__ unsigned long long s_key[KN];
    __shared__ unsigned char s_path[KN][WN];
    __shared__ float s_phi[KN][NBND];
    __shared__ int s_we[KN];
    __shared__ int s_e[KN];

    // stage masks + snr into LDS (coalesced)
    const unsigned* Eb = Em + (size_t)b * 127 * KN;
    const float* Sb = snrP + (size_t)b * WN * KN;
    for (int i = lane; i < 127 * KN; i += 64) sm_mask[i] = Eb[i];
    for (int i = lane; i < WN * KN; i += 64) sm_snr[i] = Sb[i];
    if (lane < KN) { s_key[lane] = 0ull; s_we[lane] = -1; }
    __syncthreads();

    if (lane < KN) {
        const int kn = lane;
        float sn0 = sm_snr[kn];
        float best = (sn0 > 0.0f) ? sn0 : NEGF;   // ext folded: NEG when not extendable
        int root = kn;
        for (int w = 1; w < WN; ++w) {
            unsigned mask = sm_mask[(w - 1) * KN + kn];
            float sn = sm_snr[w * KN + kn];
            // union of all lanes' masks -> uniform sparse loop (all lanes active)
            unsigned un = mask;
            un |= __shfl_xor(un, 1);
            un |= __shfl_xor(un, 2);
            un |= __shfl_xor(un, 4);
            un |= __shfl_xor(un, 8);
            un |= __shfl_xor(un, 16);
            float v = NEGF;
            int idx = 0;
            while (un) {                           // ascending bits = first-argmax
                int i = __ffs(un) - 1;
                un &= un - 1;
                float bv = __shfl(best, i);        // uniform control: all 32 lanes active
                if ((mask >> i) & 1u) {
                    if (bv > v) { v = bv; idx = i; }
                }
            }
            bool reached = v > -5e29f;             // bf > NEG*0.5
            int nr = __shfl(root, idx);
            s_prev[w][kn] = reached ? (signed char)idx : (signed char)-1;
            if (reached) {
                best = v + sn;                     // te
                root = nr;
                unsigned ub = __float_as_uint(best);
                ub ^= (ub >> 31) ? 0xFFFFFFFFu : 0x80000000u;
                unsigned e = (unsigned)(w * KN + kn);
                unsigned long long key =
                    ((unsigned long long)ub << 32) | (unsigned long long)(0xFFFFFFFFu - e);
                atomicMax(&s_key[root], key);
            } else {
                best = NEGF;
            }
        }
    }
    __syncthreads();

    const float* T = tok + (size_t)b * WN * KN * CN;

    // backtrack selected chain + phase cumsum (one lane per root)
    if (lane < KN) {
        unsigned long long key = s_key[lane];
        if (key != 0ull) {
            int e = (int)(0xFFFFFFFFu - (unsigned)(key & 0xFFFFFFFFull));
            int we = e >> 5;
            s_we[lane] = we;
            s_e[lane] = e;
            int k = e & 31;
            for (int w = we; w > 0; --w) {
                s_path[lane][w] = (unsigned char)k;
                k = s_prev[w][k];
            }
            s_path[lane][0] = (unsigned char)k;

            int p0 = s_path[lane][0];
            float ps0 = T[p0 * CN + 7];
            float pe_prev = T[p0 * CN + 8];
            float cum = ps0;
            s_phi[lane][0] = cum;
            cum = cum + (pe_prev - ps0);           // d_first
            s_phi[lane][1] = cum;
            for (int j = 1; j <= we; ++j) {
                int pj = s_path[lane][j];
                float psj = T[(j * KN + pj) * CN + 7];
                float pej = T[(j * KN + pj) * CN + 8];
                float d = wrapf(psj - pe_prev) + pej - psj;   // d_gen
                cum += d;
                s_phi[lane][j + 1] = cum;
                pe_prev = pej;
            }
        }
    }
    __syncthreads();

    // write anchors for selected chains (<=32 short rows per batch)
    float* Ob = out + (size_t)b * (WN * KN) * NBND * 4;
    for (int u = lane; u < KN * NBND; u += 64) {
        int r  = u / NBND;
        int bp = u - r * NBND;
        int we = s_we[r];
        if (we < 0) continue;
        int L = we + 1;
        if (bp > L) continue;
        float aA, at, af;
        if (bp == 0) {
            const float* Tq = T + (int)s_path[r][0] * CN;
            at = Tq[1]; af = Tq[3]; aA = Tq[5];
        } else if (bp == L) {
            const float* Tq = T + (we * KN + (int)s_path[r][we]) * CN;
            at = Tq[2]; af = Tq[4]; aA = Tq[6];
        } else {
            const float* Ta = T + ((bp - 1) * KN + (int)s_path[r][bp - 1]) * CN;
            const float* Tb = T + (bp * KN + (int)s_path[r][bp]) * CN;
            at = (Ta[2] + Tb[1]) * 0.5f;
            af = (Ta[4] + Tb[3]) * 0.5f;
            aA = (Ta[6] + Tb[5]) * 0.5f;
        }
        float4 val;
        val.x = aA; val.y = at; val.z = s_phi[r][bp]; val.w = af;
        *reinterpret_cast<float4*>(Ob + ((size_t)s_e[r] * NBND + bp) * 4) = val;
    }
}

extern "C" void kernel_launch(void* const* d_in, const int* in_sizes, int n_in,
                              void* d_out, int out_size, void* d_ws, size_t ws_size,
                              hipStream_t stream) {
    const float* tok = (const float*)d_in[0];
    float* out = (float*)d_out;
    int B = in_sizes[0] / (WN * KN * CN);

    // workspace layout: edge masks then packed snr
    unsigned* Em = (unsigned*)d_ws;
    float* snrP = (float*)((char*)d_ws + (size_t)B * 127 * KN * sizeof(unsigned) + 256);

    int total4 = out_size / 4;
    hipLaunchKernelGGL(edge_kernel, dim3(B * 127), dim3(1024), 0, stream,
                       tok, Em, snrP, (float4*)out, total4);
    hipLaunchKernelGGL(dp_kernel, dim3(B), dim3(64), 0, stream,
                       tok, Em, snrP, out);
}

// Round 3
// 98.569 us; speedup vs baseline: 2.0969x; 2.0969x over previous
//
#include <hip/hip_runtime.h>

#define WN 128
#define KN 32
#define CN 9
#define NBND 129           // W+1 boundary positions
#define NEGF (-1e30f)

// jnp floor-mod based wrap: (x + pi) % (2pi) - pi
__device__ __forceinline__ float wrapf(float x) {
    const float PIf  = 3.14159265358979323846f;
    const float TPIf = 6.28318530717958647692f;
    float a = x + PIf;
    float r = fmodf(a, TPIf);
    if (r < 0.0f) r += TPIf;
    return r - PIf;
}

// Kernel 1: edge feasibility masks (32-bit kp-mask per (b,w,kn)) + packed snr.
__global__ __launch_bounds__(1024) void edge_kernel(const float* __restrict__ tok,
                                                    unsigned* __restrict__ Em,
                                                    float* __restrict__ snrP) {
    const int b = blockIdx.x / 127;
    const int w = blockIdx.x - b * 127;        // 0..126 (prev window)
    const int t = threadIdx.x;
    const int kp = t & 31;                     // prev token
    const int kn = t >> 5;                     // cur token (0..31)
    const float* Tp = tok + (((size_t)b * WN + w) * KN + kp) * CN;
    const float* Tc = tok + (((size_t)b * WN + w + 1) * KN + kn) * CN;

    float fe = Tp[4], fs = Tc[3];
    float fm = (fe + fs) * 0.5f;
    bool ok_f = (fm <= 0.0f) || (fabsf(fe - fs) / (fm > 0.0f ? fm : 1.0f) <= 0.05f);
    float dphi = wrapf(Tc[7] - Tp[8]);
    bool ok_p = fabsf(dphi) <= 0.5f;
    float ae = Tp[6], an = Tc[5];
    float am = fmaxf(ae, an);
    bool ok_a = (am <= 0.0f) || (fabsf(ae - an) / (am > 0.0f ? am : 1.0f) <= 0.5f);
    bool ok = (Tp[0] > 0.0f) && (Tc[0] > 0.0f) && ok_f && ok_p && ok_a;

    unsigned long long bal = __ballot(ok);
    int lw = t & 63;
    if (lw == 0)       Em[((size_t)b * 127 + w) * KN + kn] = (unsigned)(bal & 0xffffffffull);
    else if (lw == 32) Em[((size_t)b * 127 + w) * KN + kn] = (unsigned)(bal >> 32);

    if (kp == 0) snrP[((size_t)b * WN + (w + 1)) * KN + kn] = Tc[0];
    if (w == 0 && t < KN) snrP[(size_t)b * WN * KN + t] = tok[(((size_t)b * WN) * KN + t) * CN + 0];
}

// Kernel 2 (mega): blocks 0..B-1 do per-batch DP + greedy + backtrack + anchors
// into ws staging; blocks B.. zero-fill the 135MB output concurrently.
__global__ __launch_bounds__(1024) void mega_kernel(const float* __restrict__ tok,
                                                    const unsigned* __restrict__ Em,
                                                    const float* __restrict__ snrP,
                                                    float4* __restrict__ anchors,
                                                    int* __restrict__ meta,
                                                    float4* __restrict__ outz,
                                                    long total4, int B) {
    const int bid = blockIdx.x;
    if (bid >= B) {
        // ---- zero-fill (write-bound ~24us across 2032 blocks)
        long i = (long)(bid - B) * 1024 + threadIdx.x;
        long stride = (long)(gridDim.x - B) * 1024;
        float4 z = make_float4(0.f, 0.f, 0.f, 0.f);
        for (; i < total4; i += stride) outz[i] = z;
        return;
    }

    const int b = bid;
    const int t = threadIdx.x;
    const float* T = tok + (size_t)b * WN * KN * CN;

    __shared__ unsigned sm_mask[127 * KN];
    __shared__ float sm_snr[WN * KN];
    __shared__ float sm_tot[WN * KN];
    __shared__ signed char sm_prev[WN * KN];
    __shared__ signed char sm_root[WN * KN];
    __shared__ float s_bb[2][KN];              // best carry, double-buffered
    __shared__ int s_rb[2][KN];                // root carry
    __shared__ unsigned long long s_key[KN];
    __shared__ unsigned char s_path[KN][WN];
    __shared__ float s_d[KN][NBND];
    __shared__ int s_we[KN];

    // ---- Phase A: stage masks + snr (all 16 waves)
    const unsigned* Eb = Em + (size_t)b * 127 * KN;
    const float* Sb = snrP + (size_t)b * WN * KN;
    for (int i = t; i < 127 * KN; i += 1024) sm_mask[i] = Eb[i];
    for (int i = t; i < WN * KN; i += 1024) sm_snr[i] = Sb[i];
    if (t < KN) s_key[t] = 0ull;
    __syncthreads();

    // ---- Phase B: serial Viterbi DP, wave 0 only (others park at next barrier)
    if (t < 64) {
        const int kn = t & 31;
        const int half = t >> 5;
        __builtin_amdgcn_s_setprio(1);
        if (t < KN) {
            float s0 = sm_snr[kn];
            s_bb[0][kn] = (s0 > 0.0f) ? s0 : NEGF;
            s_rb[0][kn] = kn;
        }
        for (int w = 1; w < WN; ++w) {
            const int rb = (w - 1) & 1, wb = w & 1;
            unsigned mask = sm_mask[(w - 1) * KN + kn];
            float sn = sm_snr[w * KN + kn];
            unsigned mh = (mask >> (half * 16)) & 0xffffu;
            float v = NEGF;
            int idx = 0;
            #pragma unroll
            for (int i = 0; i < 16; ++i) {       // 16 independent LDS broadcasts
                float bv = s_bb[rb][half * 16 + i];
                if (((mh >> i) & 1u) && (bv > v)) { v = bv; idx = half * 16 + i; }
            }
            // cross-half combine; prefer lower kp index on ties (first-argmax)
            float ov = __shfl_xor(v, 32);
            int oidx = __shfl_xor(idx, 32);
            if (ov > v || (ov == v && oidx < idx)) { v = ov; idx = oidx; }
            bool reached = v > -5e29f;           // bf > NEG*0.5
            float te = v + sn;
            if (half == 0) {
                int nr = reached ? s_rb[rb][idx] : 0;
                s_bb[wb][kn] = reached ? te : NEGF;
                s_rb[wb][kn] = nr;
                sm_tot[w * KN + kn] = te;        // only consumed when prev>=0
                sm_prev[w * KN + kn] = reached ? (signed char)idx : (signed char)-1;
                sm_root[w * KN + kn] = (signed char)nr;
            }
        }
        __builtin_amdgcn_s_setprio(0);
    }
    __syncthreads();

    // ---- Phase C: greedy == per-root argmax(total), tie -> lowest flat idx
    for (int e = KN + t; e < WN * KN; e += 1024) {
        if (sm_prev[e] >= 0) {
            int r = sm_root[e];
            unsigned ub = __float_as_uint(sm_tot[e]);
            ub ^= (ub >> 31) ? 0xFFFFFFFFu : 0x80000000u;
            unsigned long long key =
                ((unsigned long long)ub << 32) | (unsigned long long)(0xFFFFFFFFu - (unsigned)e);
            atomicMax(&s_key[r], key);
        }
    }
    __syncthreads();

    // ---- Phase D: backtrack selected chain per root (32 lanes in parallel)
    if (t < KN) {
        unsigned long long key = s_key[t];
        int we = -1, e = -1;
        if (key != 0ull) {
            e = (int)(0xFFFFFFFFu - (unsigned)(key & 0xFFFFFFFFull));
            we = e >> 5;
            int k = e & 31;
            for (int w = we; w > 0; --w) {
                s_path[t][w] = (unsigned char)k;
                k = sm_prev[w * KN + k];
            }
            s_path[t][0] = (unsigned char)k;
        }
        s_we[t] = we;
        meta[b * KN + t] = we;
        meta[(size_t)B * KN + b * KN + t] = e;
    }
    __syncthreads();

    // ---- Phase E: parallel d_j + anchor A/t/f into ws staging (all waves)
    for (int u = t; u < KN * NBND; u += 1024) {
        int r = u / NBND, bp = u - r * NBND;
        int we = s_we[r];
        if (we < 0) continue;
        if (bp <= we) {                          // phase increment d[bp]
            float dv;
            int pj = s_path[r][bp];
            if (bp == 0) {
                const float* Tq = T + pj * CN;
                dv = Tq[8] - Tq[7];              // d_first = pe0 - ps0
            } else {
                int pm = s_path[r][bp - 1];
                float pe_prev = T[((bp - 1) * KN + pm) * CN + 8];
                float psj = T[(bp * KN + pj) * CN + 7];
                float pej = T[(bp * KN + pj) * CN + 8];
                dv = wrapf(psj - pe_prev) + pej - psj;
            }
            s_d[r][bp] = dv;
        }
        int L = we + 1;
        if (bp <= L) {
            float aA, at, af;
            if (bp == 0) {
                const float* Tq = T + (int)s_path[r][0] * CN;
                at = Tq[1]; af = Tq[3]; aA = Tq[5];
            } else if (bp == L) {
                const float* Tq = T + (we * KN + (int)s_path[r][we]) * CN;
                at = Tq[2]; af = Tq[4]; aA = Tq[6];
            } else {
                const float* Ta = T + ((bp - 1) * KN + (int)s_path[r][bp - 1]) * CN;
                const float* Tb = T + (bp * KN + (int)s_path[r][bp]) * CN;
                at = (Ta[2] + Tb[1]) * 0.5f;
                af = (Ta[4] + Tb[3]) * 0.5f;
                aA = (Ta[6] + Tb[5]) * 0.5f;
            }
            float* arow = (float*)(anchors + ((size_t)b * KN + r) * NBND + bp);
            arow[0] = aA; arow[1] = at; arow[3] = af;   // z written in Phase F
        }
    }
    __syncthreads();

    // ---- Phase F: serial phase cumsum per root (32 lanes in parallel)
    if (t < KN && s_we[t] >= 0) {
        int we = s_we[t];
        int p0 = s_path[t][0];
        float cum = T[p0 * CN + 7];              // ps0
        float* arow = (float*)(anchors + ((size_t)b * KN + t) * NBND);
        arow[2] = cum;
        for (int j = 0; j <= we; ++j) {
            cum += s_d[t][j];
            arow[(j + 1) * 4 + 2] = cum;
        }
    }
}

// Kernel 3: scatter the <=32 finished anchor rows per batch over the zeros.
__global__ __launch_bounds__(1024) void scatter_kernel(const float4* __restrict__ anchors,
                                                       const int* __restrict__ meta,
                                                       float4* __restrict__ out, int B) {
    const int b = blockIdx.x;
    const int t = threadIdx.x;
    for (int u = t; u < KN * NBND; u += 1024) {
        int r = u / NBND, bp = u - r * NBND;
        int we = meta[b * KN + r];
        if (we < 0 || bp > we + 1) continue;
        int e = meta[(size_t)B * KN + b * KN + r];
        out[((size_t)b * (WN * KN) + e) * NBND + bp] =
            anchors[((size_t)b * KN + r) * NBND + bp];
    }
}

extern "C" void kernel_launch(void* const* d_in, const int* in_sizes, int n_in,
                              void* d_out, int out_size, void* d_ws, size_t ws_size,
                              hipStream_t stream) {
    const float* tok = (const float*)d_in[0];
    int B = in_sizes[0] / (WN * KN * CN);

    size_t off = 0;
    unsigned* Em = (unsigned*)d_ws;
    off += (size_t)B * 127 * KN * sizeof(unsigned);
    off = (off + 255) & ~(size_t)255;
    float* snrP = (float*)((char*)d_ws + off);
    off += (size_t)B * WN * KN * sizeof(float);
    off = (off + 255) & ~(size_t)255;
    float4* anchors = (float4*)((char*)d_ws + off);
    off += (size_t)B * KN * NBND * sizeof(float4);
    off = (off + 255) & ~(size_t)255;
    int* meta = (int*)((char*)d_ws + off);

    long total4 = (long)out_size / 4;

    hipLaunchKernelGGL(edge_kernel, dim3(B * 127), dim3(1024), 0, stream, tok, Em, snrP);
    hipLaunchKernelGGL(mega_kernel, dim3(B + 2032), dim3(1024), 0, stream,
                       tok, Em, snrP, anchors, meta, (float4*)d_out, total4, B);
    hipLaunchKernelGGL(scatter_kernel, dim3(B), dim3(1024), 0, stream,
                       anchors, meta, (float4*)d_out, B);
}